// Round 5
// baseline (554.955 us; speedup 1.0000x reference)
//
#include <hip/hip_runtime.h>
#include <stdint.h>

// TransformerEncoderLayer: B=4 S=2048 D=1024 H=16 DH=64 F=4096, fp32 in/out.
// R11: GEMM core deep-pipelined (T3/T4). R10 counters: W2 gemm at 99us =
// 930 cy/iter-slot = one HBM latency -> 1-deep prefetch was the limiter.
//  - 4 LDS buffers (64KB), 3 tiles in flight: iter t waits vmcnt(8) (counted,
//    never 0 in-loop), raw s_barrier + sched_barrier(0), issues tile t+3.
//    Period floor latency/3 ~ 310cy. Epilogue drains 8->4->0.
//  - bias preloaded to regs before the K-loop (no stray VMEM in vmcnt count).
//  - chunk-XOR LDS swizzle, both-sides (pre-swizzled global source since
//    global_load_lds writes linearly; XOR on ds_read): 8-way -> ~2-4-way
//    bank conflicts on the frag reads.
// R10 flash attention kept (32x32 MFMA, in-register softmax via cvt_pk +
// permlane32_swap, XCD-colocated K/V). R8 XCD y-chunk 1D GEMM grids kept.

typedef unsigned short u16;
typedef __attribute__((ext_vector_type(8))) short short8;
typedef __attribute__((ext_vector_type(4))) float f32x4;
typedef __attribute__((ext_vector_type(16))) float f32x16;

__device__ __forceinline__ u16 f2bf(float f) {
  union { float f; unsigned u; } v; v.f = f;
  unsigned r = (v.u + 0x7fffu + ((v.u >> 16) & 1u)) >> 16;
  return (u16)r;
}

__device__ __forceinline__ void gl_lds16(const u16* g, u16* l) {
  __builtin_amdgcn_global_load_lds(
      (const __attribute__((address_space(1))) unsigned int*)g,
      (__attribute__((address_space(3))) unsigned int*)l, 16, 0, 0);
}

// pack two fp32 -> bf16x2 with RNE rounding (1 instr)
__device__ __forceinline__ unsigned cvtpk(float lo, float hi) {
  unsigned r;
  asm("v_cvt_pk_bf16_f32 %0, %1, %2" : "=v"(r) : "v"(lo), "v"(hi));
  return r;
}
// swap lanes 0-31 of a with lanes 32-63 of b (both updated in place)
__device__ __forceinline__ void pl32_swap(unsigned& a, unsigned& b) {
  asm("v_permlane32_swap_b32 %0, %1" : "+v"(a), "+v"(b));
}

// ---------------- cast / transpose kernels ----------------

__global__ __launch_bounds__(256) void transpose_cast(const float* __restrict__ W,
                                                      u16* __restrict__ WT,
                                                      int K, int N) {
  __shared__ u16 T[64 * 72];
  const int tid = threadIdx.x;
  const long n0 = (long)blockIdx.x * 64, k0 = (long)blockIdx.y * 64;
#pragma unroll
  for (int i = 0; i < 4; i++) {
    int c = tid + i * 256;
    int kr = c >> 4, nc = (c & 15) * 4;
    float4 v = *(const float4*)(W + (k0 + kr) * N + n0 + nc);
    T[(nc + 0) * 72 + kr] = f2bf(v.x);
    T[(nc + 1) * 72 + kr] = f2bf(v.y);
    T[(nc + 2) * 72 + kr] = f2bf(v.z);
    T[(nc + 3) * 72 + kr] = f2bf(v.w);
  }
  __syncthreads();
#pragma unroll
  for (int i = 0; i < 2; i++) {
    int c = tid + i * 256;
    int nr = c >> 3, kc = (c & 7) * 8;
    *(uint4*)(WT + (n0 + nr) * K + k0 + kc) = *(const uint4*)(T + nr * 72 + kc);
  }
}

__global__ __launch_bounds__(256) void transpose_cast_qkv(const float* __restrict__ Wq,
                                                          const float* __restrict__ Wk,
                                                          const float* __restrict__ Wv,
                                                          u16* __restrict__ WT) {
  __shared__ u16 T[64 * 72];
  const int tid = threadIdx.x;
  const int n0 = blockIdx.x * 64, k0 = blockIdx.y * 64;
  const float* W = (n0 < 1024) ? Wq : (n0 < 2048 ? Wk : Wv);
  const int h = (n0 & 1023) >> 6;
#pragma unroll
  for (int i = 0; i < 4; i++) {
    int c = tid + i * 256;
    int kr = c >> 4, ec = (c & 15) * 4;
    float4 v = *(const float4*)(W + ((long)h * 1024 + k0 + kr) * 64 + ec);
    T[(ec + 0) * 72 + kr] = f2bf(v.x);
    T[(ec + 1) * 72 + kr] = f2bf(v.y);
    T[(ec + 2) * 72 + kr] = f2bf(v.z);
    T[(ec + 3) * 72 + kr] = f2bf(v.w);
  }
  __syncthreads();
#pragma unroll
  for (int i = 0; i < 2; i++) {
    int c = tid + i * 256;
    int nr = c >> 3, kc = (c & 7) * 8;
    *(uint4*)(WT + ((long)(n0 + nr)) * 1024 + k0 + kc) = *(const uint4*)(T + nr * 72 + kc);
  }
}

__global__ __launch_bounds__(256) void cast_bf16(const float* __restrict__ x, u16* __restrict__ y) {
  const long i = ((long)blockIdx.x * 256 + threadIdx.x) * 8;
  float4 a = *(const float4*)(x + i);
  float4 b = *(const float4*)(x + i + 4);
  uint4 o;
  o.x = (unsigned)f2bf(a.x) | ((unsigned)f2bf(a.y) << 16);
  o.y = (unsigned)f2bf(a.z) | ((unsigned)f2bf(a.w) << 16);
  o.z = (unsigned)f2bf(b.x) | ((unsigned)f2bf(b.y) << 16);
  o.w = (unsigned)f2bf(b.z) | ((unsigned)f2bf(b.w) << 16);
  *(uint4*)(y + i) = o;
}

__global__ __launch_bounds__(256) void build_bcat(const float* __restrict__ bq,
                                                  const float* __restrict__ bk,
                                                  const float* __restrict__ bv,
                                                  float* __restrict__ bcat) {
  int i = blockIdx.x * 256 + threadIdx.x;  // 0..3071
  const float* s = (i < 1024) ? bq : (i < 2048 ? bk : bv);
  bcat[i] = s[i & 1023];
}

// ---------------- GEMM core ----------------
// 1D grid, nb = XT*64 blocks. Decode: xcd = id&7 owns M-tiles [8*xcd, 8*xcd+8)
// for ALL N-tiles. 4-buffer LDS pipeline, 3 tiles in flight, counted vmcnt:
//   iter t: wait vmcnt(8) [tiles t+1,t+2 stay in flight] -> s_barrier ->
//   sched_barrier(0) -> issue tile t+3 -> ds_read frags -> MFMA.
// Chunk-XOR swizzle: LDS[row][c] holds global[row][c ^ (row&3)] (source
// pre-swizzled; global_load_lds dest must stay linear). Read chunk quad ->
// LDS chunk quad ^ (l15&3).
#define GEMM_SETUP                                                                 \
  __shared__ __align__(16) u16 As[4][4096];                                        \
  __shared__ __align__(16) u16 Bs[4][4096];                                        \
  const int tid = threadIdx.x;                                                     \
  const int wave = tid >> 6, lane = tid & 63, quad = lane >> 4, l15 = lane & 15;   \
  const int wm = (wave >> 1) * 64, wn = (wave & 1) * 64;                           \
  const int id = blockIdx.x, xcd = id & 7, ii = id >> 3;                           \
  const long m0 = (long)(xcd * 8 + (ii & 7)) * 128, n0 = (long)(ii >> 3) * 128;    \
  const int srow = tid >> 2, sc = (tid & 3) ^ (srow & 3);                          \
  const u16* Ag = A + (m0 + srow) * K + sc * 8;                                    \
  const u16* Bg = B + (n0 + srow) * K + sc * 8;                                    \
  const int cx = quad ^ (l15 & 3);                                                 \
  f32x4 acc[4][4] = {};                                                            \
  _Pragma("unroll") for (int p = 0; p < 3; p++) {                                  \
    gl_lds16(Ag + p * 32, &As[p][tid * 8]);                                        \
    gl_lds16(Ag + (long)64 * K + p * 32, &As[p][tid * 8 + 2048]);                  \
    gl_lds16(Bg + p * 32, &Bs[p][tid * 8]);                                        \
    gl_lds16(Bg + (long)64 * K + p * 32, &Bs[p][tid * 8 + 2048]);                  \
  }

#define GEMM_KLOOP                                                                 \
  for (int k0 = 0; k0 < K; k0 += 32) {                                             \
    if (K - k0 >= 96) asm volatile("s_waitcnt vmcnt(8)" ::: "memory");             \
    else if (K - k0 == 64) asm volatile("s_waitcnt vmcnt(4)" ::: "memory");        \
    else asm volatile("s_waitcnt vmcnt(0)" ::: "memory");                          \
    __builtin_amdgcn_s_barrier();                                                  \
    __builtin_amdgcn_sched_barrier(0);                                             \
    const int cur = (k0 >> 5) & 3;                                                 \
    if (k0 + 96 < K) {                                                             \
      const int nb = (cur + 3) & 3;                                                \
      gl_lds16(Ag + k0 + 96, &As[nb][tid * 8]);                                    \
      gl_lds16(Ag + (long)64 * K + k0 + 96, &As[nb][tid * 8 + 2048]);              \
      gl_lds16(Bg + k0 + 96, &Bs[nb][tid * 8]);                                    \
      gl_lds16(Bg + (long)64 * K + k0 + 96, &Bs[nb][tid * 8 + 2048]);              \
    }                                                                              \
    short8 af[4], bfr[4];                                                          \
    _Pragma("unroll") for (int t = 0; t < 4; t++)                                  \
        af[t] = *(const short8*)(&As[cur][(wm + t * 16 + l15) * 32 + cx * 8]);     \
    _Pragma("unroll") for (int t = 0; t < 4; t++)                                  \
        bfr[t] = *(const short8*)(&Bs[cur][(wn + t * 16 + l15) * 32 + cx * 8]);    \
    _Pragma("unroll") for (int i = 0; i < 4; i++)                                  \
        _Pragma("unroll") for (int j = 0; j < 4; j++)                              \
            acc[i][j] = __builtin_amdgcn_mfma_f32_16x16x32_bf16(af[i], bfr[j],     \
                                                                acc[i][j], 0, 0, 0); \
  }

// MODE 0: fp32 out. MODE 1: bf16 out. MODE 2: bf16 + relu.
template <int MODE>
__global__ __launch_bounds__(256) void gemm_bt(const u16* __restrict__ A, const u16* __restrict__ B,
                                               const float* __restrict__ bias, void* __restrict__ Cout,
                                               int K, int N) {
  GEMM_SETUP
  float bb[4];
#pragma unroll
  for (int j = 0; j < 4; j++) bb[j] = bias[n0 + wn + j * 16 + l15];
  GEMM_KLOOP
#pragma unroll
  for (int i = 0; i < 4; i++) {
#pragma unroll
    for (int j = 0; j < 4; j++) {
      const long col = n0 + wn + j * 16 + l15;
      const long rowb = m0 + wm + i * 16 + quad * 4;
#pragma unroll
      for (int r = 0; r < 4; r++) {
        float v = acc[i][j][r] + bb[j];
        if (MODE == 2) v = fmaxf(v, 0.f);
        if (MODE == 0)
          ((float*)Cout)[(rowb + r) * N + col] = v;
        else
          ((u16*)Cout)[(rowb + r) * N + col] = f2bf(v);
      }
    }
  }
}

// QKV GEMM: Q cols scaled by 0.125*log2e (softmax done in exp2 domain),
// K cols plain -> QKb [8192][2048]; V cols transposed -> Vt[bh][e][2048 s].
__global__ __launch_bounds__(256) void gemm_qkv(const u16* __restrict__ A, const u16* __restrict__ B,
                                                const float* __restrict__ bias,
                                                u16* __restrict__ QKb, u16* __restrict__ Vt, int K) {
  GEMM_SETUP
  float bb[4];
#pragma unroll
  for (int j = 0; j < 4; j++) bb[j] = bias[n0 + wn + j * 16 + l15];
  GEMM_KLOOP
#pragma unroll
  for (int i = 0; i < 4; i++) {
#pragma unroll
    for (int j = 0; j < 4; j++) {
      const int col0 = (int)n0 + wn + j * 16;
      const int col = col0 + l15;
      const long rowb = m0 + wm + i * 16 + quad * 4;
      if (col0 < 1024) {
#pragma unroll
        for (int r = 0; r < 4; r++)
          QKb[(rowb + r) * 2048 + col] = f2bf((acc[i][j][r] + bb[j]) * 0.1803368801f);
      } else if (col0 < 2048) {
#pragma unroll
        for (int r = 0; r < 4; r++)
          QKb[(rowb + r) * 2048 + col] = f2bf(acc[i][j][r] + bb[j]);
      } else {
        const int ec = col - 2048;
        const int bq = (int)(rowb >> 11), s = (int)(rowb & 2047);
        uint2 p;
        p.x = (unsigned)f2bf(acc[i][j][0] + bb[j]) | ((unsigned)f2bf(acc[i][j][1] + bb[j]) << 16);
        p.y = (unsigned)f2bf(acc[i][j][2] + bb[j]) | ((unsigned)f2bf(acc[i][j][3] + bb[j]) << 16);
        *(uint2*)(Vt + ((long)(bq * 16 + (ec >> 6)) * 64 + (ec & 63)) * 2048 + s) = p;
      }
    }
  }
}

// ---------------- flash attention (32x32x16 MFMA, in-register softmax) -------
// QKb [8192][2048] bf16 (Q pre-scaled by 0.125*log2e, K plain), Vt[64][64][2048].
// Grid (64 bh, 8 qt) of 256-thread blocks; id%8 = bh%8 -> all qt blocks of a
// bh share an XCD; per-XCD K/V set = 4 MB = L2. 4 waves/block; wave owns
// 64 q rows (2 j-tiles of 32) x 64 k per step.

// stage one 64x64 bf16 tile (row stride 2048) into 8KB LDS, swizzled; 256 thr
__device__ __forceinline__ void stage_tile(const u16* __restrict__ g, u16* __restrict__ lds, int tid) {
#pragma unroll
  for (int i = 0; i < 2; i++) {
    const int s = i * 256 + tid;
    const int r = s >> 3, cs = s & 7;
    const int c = cs ^ (r & 7);
    gl_lds16(g + (long)r * 2048 + c * 8, lds + s * 8);
  }
}
// read a 16B fragment (row, 16B-chunk) from a swizzled tile
__device__ __forceinline__ short8 frag(const u16* __restrict__ buf, int row, int chunk) {
  const int slot = row * 8 + (chunk ^ (row & 7));
  return *(const short8*)(buf + slot * 8);
}

__global__ __launch_bounds__(256, 2) void flash_attn(const u16* __restrict__ QKb,
                                                     const u16* __restrict__ Vt,
                                                     u16* __restrict__ ctx) {
  __shared__ __align__(16) u16 Kbuf[2][4096];
  __shared__ __align__(16) u16 Vbuf[2][4096];
  const int tid = threadIdx.x, wave = tid >> 6, lane = tid & 63;
  const int l31 = lane & 31, hi = lane >> 5;
  const int bh = blockIdx.x, b = bh >> 4, h = bh & 15;
  const int qt = blockIdx.y;  // 0..7, block covers q rows qt*256..+255
  const long qbase = (long)b * 2048 + qt * 256 + wave * 64;
  const u16* Qg = QKb + qbase * 2048 + h * 64;
  const u16* Kg = QKb + ((long)b * 2048) * 2048 + 1024 + h * 64;
  const u16* Vg = Vt + (long)bh * 64 * 2048;

  // Q B-frags: qf[j][ks]: lane q = j*32+l31, d-elems = ks*16 + hi*8 + 0..7
  short8 qf[2][4];
#pragma unroll
  for (int j = 0; j < 2; j++)
#pragma unroll
    for (int ks = 0; ks < 4; ks++)
      qf[j][ks] = *(const short8*)(Qg + (long)(j * 32 + l31) * 2048 + ks * 16 + hi * 8);

  f32x16 O[2][2] = {};   // [et][j], C-layout: col q=l31, rows e per reg map
  float rs[2] = {0.f, 0.f};  // row-sum partials (lane: q=j*32+l31, half hi)

  // preload kt=0
  stage_tile(Kg, Kbuf[0], tid);
  stage_tile(Vg, Vbuf[0], tid);

  for (int kt = 0; kt < 32; kt++) {
    __syncthreads();  // drains vmcnt: buf[kt&1] staging complete; prev readers done
    if (kt < 31) {    // issue next tile AFTER the barrier -> in flight all iteration
      stage_tile(Kg + (long)(kt + 1) * 64 * 2048, Kbuf[(kt + 1) & 1], tid);
      stage_tile(Vg + (kt + 1) * 64, Vbuf[(kt + 1) & 1], tid);
    }
    const u16* Kb = Kbuf[kt & 1];
    const u16* Vb = Vbuf[kt & 1];

#pragma unroll
    for (int m = 0; m < 2; m++) {
      // ---- S^T = K * Q for this 32-k subtile ----
      short8 ak[4];
#pragma unroll
      for (int ks = 0; ks < 4; ks++) ak[ks] = frag(Kb, m * 32 + l31, ks * 2 + hi);
      f32x16 S[2] = {};
#pragma unroll
      for (int ks = 0; ks < 4; ks++)
#pragma unroll
        for (int j = 0; j < 2; j++)
          S[j] = __builtin_amdgcn_mfma_f32_32x32x16_bf16(ak[ks], qf[j][ks], S[j], 0, 0, 0);

      // ---- P = exp2(S); row-sum; C->B-frag transpose in-register ----
      short8 pf[2][2];  // [j][ks2]
#pragma unroll
      for (int j = 0; j < 2; j++) {
#pragma unroll
        for (int r = 0; r < 16; r++) S[j][r] = __builtin_amdgcn_exp2f(S[j][r]);
        rs[j] += ((S[j][0] + S[j][1]) + (S[j][2] + S[j][3])) +
                 ((S[j][4] + S[j][5]) + (S[j][6] + S[j][7])) +
                 ((S[j][8] + S[j][9]) + (S[j][10] + S[j][11])) +
                 ((S[j][12] + S[j][13]) + (S[j][14] + S[j][15]));
        unsigned w0 = cvtpk(S[j][0], S[j][1]), w1 = cvtpk(S[j][2], S[j][3]);
        unsigned w2 = cvtpk(S[j][4], S[j][5]), w3 = cvtpk(S[j][6], S[j][7]);
        unsigned w4 = cvtpk(S[j][8], S[j][9]), w5 = cvtpk(S[j][10], S[j][11]);
        unsigned w6 = cvtpk(S[j][12], S[j][13]), w7 = cvtpk(S[j][14], S[j][15]);
        pl32_swap(w2, w0); pl32_swap(w3, w1);   // frag ks2=0: {w0,w1,w2,w3}
        pl32_swap(w6, w4); pl32_swap(w7, w5);   // frag ks2=1: {w4,w5,w6,w7}
        union { unsigned u[4]; short8 s8; } f0, f1;
        f0.u[0] = w0; f0.u[1] = w1; f0.u[2] = w2; f0.u[3] = w3;
        f1.u[0] = w4; f1.u[1] = w5; f1.u[2] = w6; f1.u[3] = w7;
        pf[j][0] = f0.s8; pf[j][1] = f1.s8;
      }

      // ---- O^T += V^T * P for this 32-k subtile ----
#pragma unroll
      for (int et = 0; et < 2; et++) {
        short8 av[2];
#pragma unroll
        for (int ks2 = 0; ks2 < 2; ks2++)
          av[ks2] = frag(Vb, et * 32 + l31, m * 4 + ks2 * 2 + hi);
#pragma unroll
        for (int j = 0; j < 2; j++)
#pragma unroll
          for (int ks2 = 0; ks2 < 2; ks2++)
            O[et][j] = __builtin_amdgcn_mfma_f32_32x32x16_bf16(av[ks2], pf[j][ks2],
                                                               O[et][j], 0, 0, 0);
      }
    }
  }

  // epilogue: finish row-sums across lane halves, scale, store
#pragma unroll
  for (int j = 0; j < 2; j++) rs[j] += __shfl_xor(rs[j], 32);
#pragma unroll
  for (int j = 0; j < 2; j++) {
    const float inv = 1.f / rs[j];
    const long row = qbase + j * 32 + l31;
#pragma unroll
    for (int et = 0; et < 2; et++)
#pragma unroll
      for (int g = 0; g < 4; g++) {
        const int e0 = et * 32 + g * 8 + hi * 4;  // C row = (reg&3) + 8*(reg>>2) + 4*hi
        uint2 p;
        p.x = (unsigned)f2bf(O[et][j][g * 4 + 0] * inv) |
              ((unsigned)f2bf(O[et][j][g * 4 + 1] * inv) << 16);
        p.y = (unsigned)f2bf(O[et][j][g * 4 + 2] * inv) |
              ((unsigned)f2bf(O[et][j][g * 4 + 3] * inv) << 16);
        *(uint2*)(ctx + row * 1024 + h * 64 + e0) = p;
      }
  }
}

// ---------------- residual add + layernorm ----------------
template <bool WB>
__global__ __launch_bounds__(256) void add_ln(const float* __restrict__ a, const float* __restrict__ c,
                                              const float* __restrict__ w, const float* __restrict__ bias,
                                              float* __restrict__ xout, u16* __restrict__ xbf) {
  const int row = blockIdx.x, tid = threadIdx.x;
  const long off = (long)row * 1024 + tid * 4;
  float4 va = *(const float4*)(a + off);
  float4 vc = *(const float4*)(c + off);
  float4 s = {va.x + vc.x, va.y + vc.y, va.z + vc.z, va.w + vc.w};
  float sum = s.x + s.y + s.z + s.w;
  float sq = s.x * s.x + s.y * s.y + s.z * s.z + s.w * s.w;
#pragma unroll
  for (int o = 32; o > 0; o >>= 1) {
    sum += __shfl_xor(sum, o);
    sq += __shfl_xor(sq, o);
  }
  __shared__ float red[8];
  const int wave = tid >> 6;
  if ((tid & 63) == 0) { red[wave] = sum; red[wave + 4] = sq; }
  __syncthreads();
  sum = red[0] + red[1] + red[2] + red[3];
  sq = red[4] + red[5] + red[6] + red[7];
  const float mean = sum * (1.f / 1024.f);
  const float var = sq * (1.f / 1024.f) - mean * mean;
  const float rstd = rsqrtf(var + 1e-5f);
  float4 vw = *(const float4*)(w + tid * 4);
  float4 vb = *(const float4*)(bias + tid * 4);
  float4 y;
  y.x = (s.x - mean) * rstd * vw.x + vb.x;
  y.y = (s.y - mean) * rstd * vw.y + vb.y;
  y.z = (s.z - mean) * rstd * vw.z + vb.z;
  y.w = (s.w - mean) * rstd * vw.w + vb.w;
  *(float4*)(xout + off) = y;
  if (WB) {
    uint2 o2;
    o2.x = (unsigned)f2bf(y.x) | ((unsigned)f2bf(y.y) << 16);
    o2.y = (unsigned)f2bf(y.z) | ((unsigned)f2bf(y.w) << 16);
    *(uint2*)(xbf + off) = o2;
  }
}

// ---------------- launch ----------------
extern "C" void kernel_launch(void* const* d_in, const int* in_sizes, int n_in,
                              void* d_out, int out_size, void* d_ws, size_t ws_size,
                              hipStream_t stream) {
  (void)in_sizes; (void)n_in; (void)out_size; (void)ws_size;
  const float* src = (const float*)d_in[0];
  const float* Wq = (const float*)d_in[1];
  const float* bq = (const float*)d_in[2];
  const float* Wk = (const float*)d_in[3];
  const float* bk = (const float*)d_in[4];
  const float* Wv = (const float*)d_in[5];
  const float* bv = (const float*)d_in[6];
  const float* Wo = (const float*)d_in[7];
  const float* bo = (const float*)d_in[8];
  const float* ln1w = (const float*)d_in[9];
  const float* ln1b = (const float*)d_in[10];
  const float* W1 = (const float*)d_in[11];
  const float* b1 = (const float*)d_in[12];
  const float* W2 = (const float*)d_in[13];
  const float* b2 = (const float*)d_in[14];
  const float* ln2w = (const float*)d_in[15];
  const float* ln2b = (const float*)d_in[16];

  char* ws = (char*)d_ws;
  u16* WqkvT = (u16*)(ws + 0);                      // 6 MB  [3072][1024]
  u16* WoT = (u16*)(ws + (6ul << 20));              // 2 MB  [1024][1024]
  u16* W1T = (u16*)(ws + (8ul << 20));              // 8 MB  [4096][1024]
  u16* W2T = (u16*)(ws + (16ul << 20));             // 8 MB  [1024][4096]
  float* bcat = (float*)(ws + (24ul << 20));        // 12 KB
  u16* srcb = (u16*)(ws + (25ul << 20));            // 16 MB [8192][1024]
  u16* QKb = (u16*)(ws + (41ul << 20));             // 32 MB [8192][2048] (Q|K)
  u16* Vt = (u16*)(ws + (73ul << 20));              // 16 MB [64 bh][64 e][2048 s]
  u16* ctxb = (u16*)(ws + (89ul << 20));            // 16 MB [8192][1024]
  float* x = (float*)(ws + (105ul << 20));          // 32 MB [8192][1024]
  u16* xb = (u16*)(ws + (137ul << 20));             // 16 MB
  u16* hb = (u16*)(ws + (41ul << 20));              // 64 MB [8192][4096] (reuses QKb+Vt+ctxb)
  float* out = (float*)d_out;                       // scratch for attn_out / ffn2

  transpose_cast_qkv<<<dim3(48, 16), 256, 0, stream>>>(Wq, Wk, Wv, WqkvT);
  transpose_cast<<<dim3(16, 16), 256, 0, stream>>>(Wo, WoT, 1024, 1024);
  transpose_cast<<<dim3(64, 16), 256, 0, stream>>>(W1, W1T, 1024, 4096);
  transpose_cast<<<dim3(16, 64), 256, 0, stream>>>(W2, W2T, 4096, 1024);
  cast_bf16<<<4096, 256, 0, stream>>>(src, srcb);
  build_bcat<<<12, 256, 0, stream>>>(bq, bk, bv, bcat);

  // 1D GEMM grids: nb = XT*64 (XT = N/128 x-tiles); in-kernel XCD y-chunk decode
  gemm_qkv<<<24 * 64, 256, 0, stream>>>(srcb, WqkvT, bcat, QKb, Vt, 1024);
  flash_attn<<<dim3(64, 8), 256, 0, stream>>>(QKb, Vt, ctxb);
  gemm_bt<0><<<8 * 64, 256, 0, stream>>>(ctxb, WoT, bo, out, 1024, 1024);
  add_ln<true><<<8192, 256, 0, stream>>>(src, out, ln1w, ln1b, x, xb);
  gemm_bt<2><<<32 * 64, 256, 0, stream>>>(xb, W1T, b1, hb, 1024, 4096);
  gemm_bt<0><<<8 * 64, 256, 0, stream>>>(hb, W2T, b2, out, 4096, 1024);
  add_ln<false><<<8192, 256, 0, stream>>>(x, out, ln2w, ln2b, out, nullptr);
}

// Round 6
// 507.613 us; speedup vs baseline: 1.0933x; 1.0933x over previous
//
#include <hip/hip_runtime.h>
#include <stdint.h>

// TransformerEncoderLayer: B=4 S=2048 D=1024 H=16 DH=64 F=4096, fp32 in/out.
// R12: R11's deep-pipeline graft REVERTED (m141-class regression: counted
// vmcnt + sched_barrier(0) without the 8-phase interleave lost 40us).
// Back to the proven R10 2-buffer stage-after-barrier core, plus:
//  - CORRECT LDS swizzle: chunk ^ ((row>>1)&3) (row bits [2:1], not [1:0] --
//    R11's row&3 left SQ_LDS_BANK_CONFLICT exactly unchanged at 8.39M).
//    Bank = (16*l15 + 4*chunk) mod 32 -> XOR with l15[2:1] gives every bank
//    exactly 2 lanes = free (m136). Applied both-sides: pre-swizzled global
//    source (global_load_lds dest must stay linear) + XOR'd ds_read.
//  - In-block split-K x2 for the two N=1024 GEMMs (Wo, FFN2): 512-thr blocks,
//    waves 0-3 = K-half 0, waves 4-7 = K-half 1, each half with its own
//    2-buffer LDS (64KB total, 2 blocks/CU) -> 4 independent tile-streams/CU
//    (TLP latency hiding per m114) vs 2 before. Halves reduced via
//    conflict-free LDS exchange; no extra global buffers.
// R10 flash attention kept (32x32 MFMA, in-register softmax via cvt_pk +
// permlane32_swap, XCD-colocated K/V). R8 XCD y-chunk 1D GEMM grids kept.

typedef unsigned short u16;
typedef __attribute__((ext_vector_type(8))) short short8;
typedef __attribute__((ext_vector_type(4))) float f32x4;
typedef __attribute__((ext_vector_type(16))) float f32x16;

__device__ __forceinline__ u16 f2bf(float f) {
  union { float f; unsigned u; } v; v.f = f;
  unsigned r = (v.u + 0x7fffu + ((v.u >> 16) & 1u)) >> 16;
  return (u16)r;
}

__device__ __forceinline__ void gl_lds16(const u16* g, u16* l) {
  __builtin_amdgcn_global_load_lds(
      (const __attribute__((address_space(1))) unsigned int*)g,
      (__attribute__((address_space(3))) unsigned int*)l, 16, 0, 0);
}

// pack two fp32 -> bf16x2 with RNE rounding (1 instr)
__device__ __forceinline__ unsigned cvtpk(float lo, float hi) {
  unsigned r;
  asm("v_cvt_pk_bf16_f32 %0, %1, %2" : "=v"(r) : "v"(lo), "v"(hi));
  return r;
}
// swap lanes 0-31 of a with lanes 32-63 of b (both updated in place)
__device__ __forceinline__ void pl32_swap(unsigned& a, unsigned& b) {
  asm("v_permlane32_swap_b32 %0, %1" : "+v"(a), "+v"(b));
}

// ---------------- cast / transpose kernels ----------------

__global__ __launch_bounds__(256) void transpose_cast(const float* __restrict__ W,
                                                      u16* __restrict__ WT,
                                                      int K, int N) {
  __shared__ u16 T[64 * 72];
  const int tid = threadIdx.x;
  const long n0 = (long)blockIdx.x * 64, k0 = (long)blockIdx.y * 64;
#pragma unroll
  for (int i = 0; i < 4; i++) {
    int c = tid + i * 256;
    int kr = c >> 4, nc = (c & 15) * 4;
    float4 v = *(const float4*)(W + (k0 + kr) * N + n0 + nc);
    T[(nc + 0) * 72 + kr] = f2bf(v.x);
    T[(nc + 1) * 72 + kr] = f2bf(v.y);
    T[(nc + 2) * 72 + kr] = f2bf(v.z);
    T[(nc + 3) * 72 + kr] = f2bf(v.w);
  }
  __syncthreads();
#pragma unroll
  for (int i = 0; i < 2; i++) {
    int c = tid + i * 256;
    int nr = c >> 3, kc = (c & 7) * 8;
    *(uint4*)(WT + (n0 + nr) * K + k0 + kc) = *(const uint4*)(T + nr * 72 + kc);
  }
}

__global__ __launch_bounds__(256) void transpose_cast_qkv(const float* __restrict__ Wq,
                                                          const float* __restrict__ Wk,
                                                          const float* __restrict__ Wv,
                                                          u16* __restrict__ WT) {
  __shared__ u16 T[64 * 72];
  const int tid = threadIdx.x;
  const int n0 = blockIdx.x * 64, k0 = blockIdx.y * 64;
  const float* W = (n0 < 1024) ? Wq : (n0 < 2048 ? Wk : Wv);
  const int h = (n0 & 1023) >> 6;
#pragma unroll
  for (int i = 0; i < 4; i++) {
    int c = tid + i * 256;
    int kr = c >> 4, ec = (c & 15) * 4;
    float4 v = *(const float4*)(W + ((long)h * 1024 + k0 + kr) * 64 + ec);
    T[(ec + 0) * 72 + kr] = f2bf(v.x);
    T[(ec + 1) * 72 + kr] = f2bf(v.y);
    T[(ec + 2) * 72 + kr] = f2bf(v.z);
    T[(ec + 3) * 72 + kr] = f2bf(v.w);
  }
  __syncthreads();
#pragma unroll
  for (int i = 0; i < 2; i++) {
    int c = tid + i * 256;
    int nr = c >> 3, kc = (c & 7) * 8;
    *(uint4*)(WT + ((long)(n0 + nr)) * 1024 + k0 + kc) = *(const uint4*)(T + nr * 72 + kc);
  }
}

__global__ __launch_bounds__(256) void cast_bf16(const float* __restrict__ x, u16* __restrict__ y) {
  const long i = ((long)blockIdx.x * 256 + threadIdx.x) * 8;
  float4 a = *(const float4*)(x + i);
  float4 b = *(const float4*)(x + i + 4);
  uint4 o;
  o.x = (unsigned)f2bf(a.x) | ((unsigned)f2bf(a.y) << 16);
  o.y = (unsigned)f2bf(a.z) | ((unsigned)f2bf(a.w) << 16);
  o.z = (unsigned)f2bf(b.x) | ((unsigned)f2bf(b.y) << 16);
  o.w = (unsigned)f2bf(b.z) | ((unsigned)f2bf(b.w) << 16);
  *(uint4*)(y + i) = o;
}

__global__ __launch_bounds__(256) void build_bcat(const float* __restrict__ bq,
                                                  const float* __restrict__ bk,
                                                  const float* __restrict__ bv,
                                                  float* __restrict__ bcat) {
  int i = blockIdx.x * 256 + threadIdx.x;  // 0..3071
  const float* s = (i < 1024) ? bq : (i < 2048 ? bk : bv);
  bcat[i] = s[i & 1023];
}

// ---------------- GEMM core (R10 structure + corrected swizzle) ----------------
// 1D grid, nb = XT*64 blocks. Decode: xcd = id&7 owns M-tiles [8*xcd, 8*xcd+8)
// for ALL N-tiles. Double-buffered LDS staging, stage-after-barrier: one
// __syncthreads per K-step; next tile's loads issued right after it.
// Swizzle: LDS[row][c] = global[row][c ^ ((row>>1)&3)]; read chunk quad ->
// physical quad ^ ((l15>>1)&3) (row bits [2:1] == l15 bits [2:1]).
#define GEMM_PROLOGUE                                                              \
  __shared__ __align__(16) u16 As[2][4096];                                        \
  __shared__ __align__(16) u16 Bs[2][4096];                                        \
  const int tid = threadIdx.x;                                                     \
  const int wave = tid >> 6, lane = tid & 63, quad = lane >> 4, l15 = lane & 15;   \
  const int wm = (wave >> 1) * 64, wn = (wave & 1) * 64;                           \
  const int id = blockIdx.x, xcd = id & 7, ii = id >> 3;                           \
  const long m0 = (long)(xcd * 8 + (ii & 7)) * 128, n0 = (long)(ii >> 3) * 128;    \
  const int srow = tid >> 2, sc = (tid & 3) ^ ((srow >> 1) & 3);                   \
  const u16* Ag = A + (m0 + srow) * K + sc * 8;                                    \
  const u16* Bg = B + (n0 + srow) * K + sc * 8;                                    \
  const int cx = (l15 >> 1) & 3;                                                   \
  f32x4 acc[4][4] = {};                                                            \
  gl_lds16(Ag, &As[0][tid * 8]);                                                   \
  gl_lds16(Ag + (long)64 * K, &As[0][tid * 8 + 2048]);                             \
  gl_lds16(Bg, &Bs[0][tid * 8]);                                                   \
  gl_lds16(Bg + (long)64 * K, &Bs[0][tid * 8 + 2048]);                             \
  for (int k0 = 0; k0 < K; k0 += 32) {                                             \
    __syncthreads(); /* drains vmcnt: buf[cur] staged; prev readers done */        \
    const int cur = (k0 >> 5) & 1;                                                 \
    if (k0 + 32 < K) {                                                             \
      gl_lds16(Ag + k0 + 32, &As[cur ^ 1][tid * 8]);                               \
      gl_lds16(Ag + (long)64 * K + k0 + 32, &As[cur ^ 1][tid * 8 + 2048]);         \
      gl_lds16(Bg + k0 + 32, &Bs[cur ^ 1][tid * 8]);                               \
      gl_lds16(Bg + (long)64 * K + k0 + 32, &Bs[cur ^ 1][tid * 8 + 2048]);         \
    }                                                                              \
    short8 af[4], bfr[4];                                                          \
    _Pragma("unroll") for (int t = 0; t < 4; t++)                                  \
        af[t] = *(const short8*)(&As[cur][(wm + t * 16 + l15) * 32 + (quad ^ cx) * 8]); \
    _Pragma("unroll") for (int t = 0; t < 4; t++)                                  \
        bfr[t] = *(const short8*)(&Bs[cur][(wn + t * 16 + l15) * 32 + (quad ^ cx) * 8]); \
    _Pragma("unroll") for (int i = 0; i < 4; i++)                                  \
        _Pragma("unroll") for (int j = 0; j < 4; j++)                              \
            acc[i][j] = __builtin_amdgcn_mfma_f32_16x16x32_bf16(af[i], bfr[j],     \
                                                                acc[i][j], 0, 0, 0); \
  }

// MODE 0: fp32 out. MODE 1: bf16 out. MODE 2: bf16 + relu.
template <int MODE>
__global__ __launch_bounds__(256) void gemm_bt(const u16* __restrict__ A, const u16* __restrict__ B,
                                               const float* __restrict__ bias, void* __restrict__ Cout,
                                               int K, int N) {
  GEMM_PROLOGUE
#pragma unroll
  for (int i = 0; i < 4; i++) {
#pragma unroll
    for (int j = 0; j < 4; j++) {
      const long col = n0 + wn + j * 16 + l15;
      const float bb = bias[col];
      const long rowb = m0 + wm + i * 16 + quad * 4;
#pragma unroll
      for (int r = 0; r < 4; r++) {
        float v = acc[i][j][r] + bb;
        if (MODE == 2) v = fmaxf(v, 0.f);
        if (MODE == 0)
          ((float*)Cout)[(rowb + r) * N + col] = v;
        else
          ((u16*)Cout)[(rowb + r) * N + col] = f2bf(v);
      }
    }
  }
}

// Split-K x2 variant for the N=1024 GEMMs (grid 512 = 2 blocks/CU): 512 thr,
// waves 0-3 compute K-half 0, waves 4-7 K-half 1 (own 2-buffer LDS) -> 4
// independent tile-streams per CU. Halves combined via conflict-free LDS
// exchange (16B/lane contiguous), then waves 0-3 store.
template <int MODE>
__global__ __launch_bounds__(512) void gemm_bt_sk(const u16* __restrict__ A, const u16* __restrict__ B,
                                                  const float* __restrict__ bias, void* __restrict__ Cout,
                                                  int K, int N) {
  __shared__ __align__(16) u16 As[2][2][4096];  // [kh][buf]
  __shared__ __align__(16) u16 Bs[2][2][4096];
  const int tid = threadIdx.x;
  const int wave = tid >> 6, lane = tid & 63, quad = lane >> 4, l15 = lane & 15;
  const int kh = wave >> 2, w4 = wave & 3;
  const int wm = (w4 >> 1) * 64, wn = (w4 & 1) * 64;
  const int id = blockIdx.x, xcd = id & 7, ii = id >> 3;
  const long m0 = (long)(xcd * 8 + (ii & 7)) * 128, n0 = (long)(ii >> 3) * 128;
  const int t = tid & 255;  // staging thread within half
  const int srow = t >> 2, sc = (t & 3) ^ ((srow >> 1) & 3);
  const int Kh = K >> 1;
  const u16* Ag = A + (m0 + srow) * K + kh * Kh + sc * 8;
  const u16* Bg = B + (n0 + srow) * K + kh * Kh + sc * 8;
  const int cx = (l15 >> 1) & 3;
  f32x4 acc[4][4] = {};
  gl_lds16(Ag, &As[kh][0][t * 8]);
  gl_lds16(Ag + (long)64 * K, &As[kh][0][t * 8 + 2048]);
  gl_lds16(Bg, &Bs[kh][0][t * 8]);
  gl_lds16(Bg + (long)64 * K, &Bs[kh][0][t * 8 + 2048]);
  for (int k0 = 0; k0 < Kh; k0 += 32) {
    __syncthreads();
    const int cur = (k0 >> 5) & 1;
    if (k0 + 32 < Kh) {
      gl_lds16(Ag + k0 + 32, &As[kh][cur ^ 1][t * 8]);
      gl_lds16(Ag + (long)64 * K + k0 + 32, &As[kh][cur ^ 1][t * 8 + 2048]);
      gl_lds16(Bg + k0 + 32, &Bs[kh][cur ^ 1][t * 8]);
      gl_lds16(Bg + (long)64 * K + k0 + 32, &Bs[kh][cur ^ 1][t * 8 + 2048]);
    }
    short8 af[4], bfr[4];
#pragma unroll
    for (int tt = 0; tt < 4; tt++)
      af[tt] = *(const short8*)(&As[kh][cur][(wm + tt * 16 + l15) * 32 + (quad ^ cx) * 8]);
#pragma unroll
    for (int tt = 0; tt < 4; tt++)
      bfr[tt] = *(const short8*)(&Bs[kh][cur][(wn + tt * 16 + l15) * 32 + (quad ^ cx) * 8]);
#pragma unroll
    for (int i = 0; i < 4; i++)
#pragma unroll
      for (int j = 0; j < 4; j++)
        acc[i][j] = __builtin_amdgcn_mfma_f32_16x16x32_bf16(af[i], bfr[j], acc[i][j], 0, 0, 0);
  }
  // cross-half reduction through LDS (reuse As/Bs; 16KB per w4; 16B/lane rows)
  __syncthreads();
  float* red = (w4 & 2) ? (float*)Bs : (float*)As;
  float* myred = red + (w4 & 1) * 4096 + lane * 4;
  if (kh == 1) {
#pragma unroll
    for (int i = 0; i < 4; i++)
#pragma unroll
      for (int j = 0; j < 4; j++)
        *(f32x4*)(myred + (i * 4 + j) * 256) = acc[i][j];
  }
  __syncthreads();
  if (kh == 0) {
#pragma unroll
    for (int i = 0; i < 4; i++) {
#pragma unroll
      for (int j = 0; j < 4; j++) {
        const f32x4 o = *(const f32x4*)(myred + (i * 4 + j) * 256);
        const long col = n0 + wn + j * 16 + l15;
        const float bb = bias[col];
        const long rowb = m0 + wm + i * 16 + quad * 4;
#pragma unroll
        for (int r = 0; r < 4; r++) {
          float v = acc[i][j][r] + o[r] + bb;
          if (MODE == 2) v = fmaxf(v, 0.f);
          if (MODE == 0)
            ((float*)Cout)[(rowb + r) * N + col] = v;
          else
            ((u16*)Cout)[(rowb + r) * N + col] = f2bf(v);
        }
      }
    }
  }
}

// QKV GEMM: Q cols scaled by 0.125*log2e (softmax done in exp2 domain),
// K cols plain -> QKb [8192][2048]; V cols transposed -> Vt[bh][e][2048 s].
__global__ __launch_bounds__(256) void gemm_qkv(const u16* __restrict__ A, const u16* __restrict__ B,
                                                const float* __restrict__ bias,
                                                u16* __restrict__ QKb, u16* __restrict__ Vt, int K) {
  GEMM_PROLOGUE
#pragma unroll
  for (int i = 0; i < 4; i++) {
#pragma unroll
    for (int j = 0; j < 4; j++) {
      const int col0 = (int)n0 + wn + j * 16;
      const int col = col0 + l15;
      const float bb = bias[col];
      const long rowb = m0 + wm + i * 16 + quad * 4;
      if (col0 < 1024) {
#pragma unroll
        for (int r = 0; r < 4; r++)
          QKb[(rowb + r) * 2048 + col] = f2bf((acc[i][j][r] + bb) * 0.1803368801f);
      } else if (col0 < 2048) {
#pragma unroll
        for (int r = 0; r < 4; r++)
          QKb[(rowb + r) * 2048 + col] = f2bf(acc[i][j][r] + bb);
      } else {
        const int ec = col - 2048;
        const int bq = (int)(rowb >> 11), s = (int)(rowb & 2047);
        uint2 p;
        p.x = (unsigned)f2bf(acc[i][j][0] + bb) | ((unsigned)f2bf(acc[i][j][1] + bb) << 16);
        p.y = (unsigned)f2bf(acc[i][j][2] + bb) | ((unsigned)f2bf(acc[i][j][3] + bb) << 16);
        *(uint2*)(Vt + ((long)(bq * 16 + (ec >> 6)) * 64 + (ec & 63)) * 2048 + s) = p;
      }
    }
  }
}

// ---------------- flash attention (32x32x16 MFMA, in-register softmax) -------
// QKb [8192][2048] bf16 (Q pre-scaled by 0.125*log2e, K plain), Vt[64][64][2048].
// Grid (64 bh, 8 qt) of 256-thread blocks; id%8 = bh%8 -> all qt blocks of a
// bh share an XCD; per-XCD K/V set = 4 MB = L2. 4 waves/block; wave owns
// 64 q rows (2 j-tiles of 32) x 64 k per step.

// stage one 64x64 bf16 tile (row stride 2048) into 8KB LDS, swizzled; 256 thr
__device__ __forceinline__ void stage_tile(const u16* __restrict__ g, u16* __restrict__ lds, int tid) {
#pragma unroll
  for (int i = 0; i < 2; i++) {
    const int s = i * 256 + tid;
    const int r = s >> 3, cs = s & 7;
    const int c = cs ^ (r & 7);
    gl_lds16(g + (long)r * 2048 + c * 8, lds + s * 8);
  }
}
// read a 16B fragment (row, 16B-chunk) from a swizzled tile
__device__ __forceinline__ short8 frag(const u16* __restrict__ buf, int row, int chunk) {
  const int slot = row * 8 + (chunk ^ (row & 7));
  return *(const short8*)(buf + slot * 8);
}

__global__ __launch_bounds__(256, 2) void flash_attn(const u16* __restrict__ QKb,
                                                     const u16* __restrict__ Vt,
                                                     u16* __restrict__ ctx) {
  __shared__ __align__(16) u16 Kbuf[2][4096];
  __shared__ __align__(16) u16 Vbuf[2][4096];
  const int tid = threadIdx.x, wave = tid >> 6, lane = tid & 63;
  const int l31 = lane & 31, hi = lane >> 5;
  const int bh = blockIdx.x, b = bh >> 4, h = bh & 15;
  const int qt = blockIdx.y;  // 0..7, block covers q rows qt*256..+255
  const long qbase = (long)b * 2048 + qt * 256 + wave * 64;
  const u16* Qg = QKb + qbase * 2048 + h * 64;
  const u16* Kg = QKb + ((long)b * 2048) * 2048 + 1024 + h * 64;
  const u16* Vg = Vt + (long)bh * 64 * 2048;

  // Q B-frags: qf[j][ks]: lane q = j*32+l31, d-elems = ks*16 + hi*8 + 0..7
  short8 qf[2][4];
#pragma unroll
  for (int j = 0; j < 2; j++)
#pragma unroll
    for (int ks = 0; ks < 4; ks++)
      qf[j][ks] = *(const short8*)(Qg + (long)(j * 32 + l31) * 2048 + ks * 16 + hi * 8);

  f32x16 O[2][2] = {};   // [et][j], C-layout: col q=l31, rows e per reg map
  float rs[2] = {0.f, 0.f};  // row-sum partials (lane: q=j*32+l31, half hi)

  // preload kt=0
  stage_tile(Kg, Kbuf[0], tid);
  stage_tile(Vg, Vbuf[0], tid);

  for (int kt = 0; kt < 32; kt++) {
    __syncthreads();  // drains vmcnt: buf[kt&1] staging complete; prev readers done
    if (kt < 31) {    // issue next tile AFTER the barrier -> in flight all iteration
      stage_tile(Kg + (long)(kt + 1) * 64 * 2048, Kbuf[(kt + 1) & 1], tid);
      stage_tile(Vg + (kt + 1) * 64, Vbuf[(kt + 1) & 1], tid);
    }
    const u16* Kb = Kbuf[kt & 1];
    const u16* Vb = Vbuf[kt & 1];

#pragma unroll
    for (int m = 0; m < 2; m++) {
      // ---- S^T = K * Q for this 32-k subtile ----
      short8 ak[4];
#pragma unroll
      for (int ks = 0; ks < 4; ks++) ak[ks] = frag(Kb, m * 32 + l31, ks * 2 + hi);
      f32x16 S[2] = {};
#pragma unroll
      for (int ks = 0; ks < 4; ks++)
#pragma unroll
        for (int j = 0; j < 2; j++)
          S[j] = __builtin_amdgcn_mfma_f32_32x32x16_bf16(ak[ks], qf[j][ks], S[j], 0, 0, 0);

      // ---- P = exp2(S); row-sum; C->B-frag transpose in-register ----
      short8 pf[2][2];  // [j][ks2]
#pragma unroll
      for (int j = 0; j < 2; j++) {
#pragma unroll
        for (int r = 0; r < 16; r++) S[j][r] = __builtin_amdgcn_exp2f(S[j][r]);
        rs[j] += ((S[j][0] + S[j][1]) + (S[j][2] + S[j][3])) +
                 ((S[j][4] + S[j][5]) + (S[j][6] + S[j][7])) +
                 ((S[j][8] + S[j][9]) + (S[j][10] + S[j][11])) +
                 ((S[j][12] + S[j][13]) + (S[j][14] + S[j][15]));
        unsigned w0 = cvtpk(S[j][0], S[j][1]), w1 = cvtpk(S[j][2], S[j][3]);
        unsigned w2 = cvtpk(S[j][4], S[j][5]), w3 = cvtpk(S[j][6], S[j][7]);
        unsigned w4 = cvtpk(S[j][8], S[j][9]), w5 = cvtpk(S[j][10], S[j][11]);
        unsigned w6 = cvtpk(S[j][12], S[j][13]), w7 = cvtpk(S[j][14], S[j][15]);
        pl32_swap(w2, w0); pl32_swap(w3, w1);   // frag ks2=0: {w0,w1,w2,w3}
        pl32_swap(w6, w4); pl32_swap(w7, w5);   // frag ks2=1: {w4,w5,w6,w7}
        union { unsigned u[4]; short8 s8; } f0, f1;
        f0.u[0] = w0; f0.u[1] = w1; f0.u[2] = w2; f0.u[3] = w3;
        f1.u[0] = w4; f1.u[1] = w5; f1.u[2] = w6; f1.u[3] = w7;
        pf[j][0] = f0.s8; pf[j][1] = f1.s8;
      }

      // ---- O^T += V^T * P for this 32-k subtile ----
#pragma unroll
      for (int et = 0; et < 2; et++) {
        short8 av[2];
#pragma unroll
        for (int ks2 = 0; ks2 < 2; ks2++)
          av[ks2] = frag(Vb, et * 32 + l31, m * 4 + ks2 * 2 + hi);
#pragma unroll
        for (int j = 0; j < 2; j++)
#pragma unroll
          for (int ks2 = 0; ks2 < 2; ks2++)
            O[et][j] = __builtin_amdgcn_mfma_f32_32x32x16_bf16(av[ks2], pf[j][ks2],
                                                               O[et][j], 0, 0, 0);
      }
    }
  }

  // epilogue: finish row-sums across lane halves, scale, store
#pragma unroll
  for (int j = 0; j < 2; j++) rs[j] += __shfl_xor(rs[j], 32);
#pragma unroll
  for (int j = 0; j < 2; j++) {
    const float inv = 1.f / rs[j];
    const long row = qbase + j * 32 + l31;
#pragma unroll
    for (int et = 0; et < 2; et++)
#pragma unroll
      for (int g = 0; g < 4; g++) {
        const int e0 = et * 32 + g * 8 + hi * 4;  // C row = (reg&3) + 8*(reg>>2) + 4*hi
        uint2 p;
        p.x = (unsigned)f2bf(O[et][j][g * 4 + 0] * inv) |
              ((unsigned)f2bf(O[et][j][g * 4 + 1] * inv) << 16);
        p.y = (unsigned)f2bf(O[et][j][g * 4 + 2] * inv) |
              ((unsigned)f2bf(O[et][j][g * 4 + 3] * inv) << 16);
        *(uint2*)(ctx + row * 1024 + h * 64 + e0) = p;
      }
  }
}

// ---------------- residual add + layernorm ----------------
template <bool WB>
__global__ __launch_bounds__(256) void add_ln(const float* __restrict__ a, const float* __restrict__ c,
                                              const float* __restrict__ w, const float* __restrict__ bias,
                                              float* __restrict__ xout, u16* __restrict__ xbf) {
  const int row = blockIdx.x, tid = threadIdx.x;
  const long off = (long)row * 1024 + tid * 4;
  float4 va = *(const float4*)(a + off);
  float4 vc = *(const float4*)(c + off);
  float4 s = {va.x + vc.x, va.y + vc.y, va.z + vc.z, va.w + vc.w};
  float sum = s.x + s.y + s.z + s.w;
  float sq = s.x * s.x + s.y * s.y + s.z * s.z + s.w * s.w;
#pragma unroll
  for (int o = 32; o > 0; o >>= 1) {
    sum += __shfl_xor(sum, o);
    sq += __shfl_xor(sq, o);
  }
  __shared__ float red[8];
  const int wave = tid >> 6;
  if ((tid & 63) == 0) { red[wave] = sum; red[wave + 4] = sq; }
  __syncthreads();
  sum = red[0] + red[1] + red[2] + red[3];
  sq = red[4] + red[5] + red[6] + red[7];
  const float mean = sum * (1.f / 1024.f);
  const float var = sq * (1.f / 1024.f) - mean * mean;
  const float rstd = rsqrtf(var + 1e-5f);
  float4 vw = *(const float4*)(w + tid * 4);
  float4 vb = *(const float4*)(bias + tid * 4);
  float4 y;
  y.x = (s.x - mean) * rstd * vw.x + vb.x;
  y.y = (s.y - mean) * rstd * vw.y + vb.y;
  y.z = (s.z - mean) * rstd * vw.z + vb.z;
  y.w = (s.w - mean) * rstd * vw.w + vb.w;
  *(float4*)(xout + off) = y;
  if (WB) {
    uint2 o2;
    o2.x = (unsigned)f2bf(y.x) | ((unsigned)f2bf(y.y) << 16);
    o2.y = (unsigned)f2bf(y.z) | ((unsigned)f2bf(y.w) << 16);
    *(uint2*)(xbf + off) = o2;
  }
}

// ---------------- launch ----------------
extern "C" void kernel_launch(void* const* d_in, const int* in_sizes, int n_in,
                              void* d_out, int out_size, void* d_ws, size_t ws_size,
                              hipStream_t stream) {
  (void)in_sizes; (void)n_in; (void)out_size; (void)ws_size;
  const float* src = (const float*)d_in[0];
  const float* Wq = (const float*)d_in[1];
  const float* bq = (const float*)d_in[2];
  const float* Wk = (const float*)d_in[3];
  const float* bk = (const float*)d_in[4];
  const float* Wv = (const float*)d_in[5];
  const float* bv = (const float*)d_in[6];
  const float* Wo = (const float*)d_in[7];
  const float* bo = (const float*)d_in[8];
  const float* ln1w = (const float*)d_in[9];
  const float* ln1b = (const float*)d_in[10];
  const float* W1 = (const float*)d_in[11];
  const float* b1 = (const float*)d_in[12];
  const float* W2 = (const float*)d_in[13];
  const float* b2 = (const float*)d_in[14];
  const float* ln2w = (const float*)d_in[15];
  const float* ln2b = (const float*)d_in[16];

  char* ws = (char*)d_ws;
  u16* WqkvT = (u16*)(ws + 0);                      // 6 MB  [3072][1024]
  u16* WoT = (u16*)(ws + (6ul << 20));              // 2 MB  [1024][1024]
  u16* W1T = (u16*)(ws + (8ul << 20));              // 8 MB  [4096][1024]
  u16* W2T = (u16*)(ws + (16ul << 20));             // 8 MB  [1024][4096]
  float* bcat = (float*)(ws + (24ul << 20));        // 12 KB
  u16* srcb = (u16*)(ws + (25ul << 20));            // 16 MB [8192][1024]
  u16* QKb = (u16*)(ws + (41ul << 20));             // 32 MB [8192][2048] (Q|K)
  u16* Vt = (u16*)(ws + (73ul << 20));              // 16 MB [64 bh][64 e][2048 s]
  u16* ctxb = (u16*)(ws + (89ul << 20));            // 16 MB [8192][1024]
  float* x = (float*)(ws + (105ul << 20));          // 32 MB [8192][1024]
  u16* xb = (u16*)(ws + (137ul << 20));             // 16 MB
  u16* hb = (u16*)(ws + (41ul << 20));              // 64 MB [8192][4096] (reuses QKb+Vt+ctxb)
  float* out = (float*)d_out;                       // scratch for attn_out / ffn2

  transpose_cast_qkv<<<dim3(48, 16), 256, 0, stream>>>(Wq, Wk, Wv, WqkvT);
  transpose_cast<<<dim3(16, 16), 256, 0, stream>>>(Wo, WoT, 1024, 1024);
  transpose_cast<<<dim3(64, 16), 256, 0, stream>>>(W1, W1T, 1024, 4096);
  transpose_cast<<<dim3(16, 64), 256, 0, stream>>>(W2, W2T, 4096, 1024);
  cast_bf16<<<4096, 256, 0, stream>>>(src, srcb);
  build_bcat<<<12, 256, 0, stream>>>(bq, bk, bv, bcat);

  // 1D GEMM grids: nb = XT*64 (XT = N/128 x-tiles); in-kernel XCD y-chunk decode
  gemm_qkv<<<24 * 64, 256, 0, stream>>>(srcb, WqkvT, bcat, QKb, Vt, 1024);
  flash_attn<<<dim3(64, 8), 256, 0, stream>>>(QKb, Vt, ctxb);
  gemm_bt_sk<0><<<8 * 64, 512, 0, stream>>>(ctxb, WoT, bo, out, 1024, 1024);
  add_ln<true><<<8192, 256, 0, stream>>>(src, out, ln1w, ln1b, x, xb);
  gemm_bt<2><<<32 * 64, 256, 0, stream>>>(xb, W1T, b1, hb, 1024, 4096);
  gemm_bt_sk<0><<<8 * 64, 512, 0, stream>>>(hb, W2T, b2, out, 4096, 1024);
  add_ln<false><<<8192, 256, 0, stream>>>(x, out, ln2w, ln2b, out, nullptr);
}